// Round 1
// 101.136 us; speedup vs baseline: 1.0110x; 1.0110x over previous
//
#include <hip/hip_runtime.h>
#include <cstdint>
#include <cmath>

#define Bb   128
#define INN  1024
#define OUTN 1024
#define A_TOT   (0.005f / 128.0f)   // fold mean-over-B (exact /2^7) into amplitude
#define INV_TAU (1.0f / 20.0f)

// round-to-nearest-even f32 -> bf16 (as uint16 in low bits)
__device__ __forceinline__ uint32_t rne_bf16(float f) {
    uint32_t u = __float_as_uint(f);
    return (u + 0x7fffu + ((u >> 16) & 1u)) >> 16;
}

// ---------------------------------------------------------------------------
// 1) prep: W transpose + IPackT + spike compaction.
//    IPackT[i*B + b] = (bf16(Iz)<<16) | bf16(Iy), Iz=e^{-dp/tau},
//    Iy=A*e^{dp/tau}.  b-minor layout so stdp stages it b128-wise.
// ---------------------------------------------------------------------------
__global__ __launch_bounds__(256) void prep_k(
    const float* __restrict__ W, const float* __restrict__ in_spikes,
    const float* __restrict__ delta_pre,
    float* __restrict__ Wt, uint32_t* __restrict__ IPackT,
    int* __restrict__ gIdx, int* __restrict__ gCount) {
    __shared__ float tile[32][33];
    const int blk = blockIdx.x;           // 0..511
    const int t   = threadIdx.x;

    // spike compaction (ballot order: deterministic across replays)
    if ((blk & 3) == 0 && t < 64) {
        const int b = blk >> 2;
        int base = 0;
#pragma unroll
        for (int c = 0; c < 16; c++) {
            float s = in_spikes[(size_t)b * INN + c * 64 + t];
            unsigned long long m = __ballot(s > 0.0f);
            if (s > 0.0f) {
                int pos = base + __popcll(m & ((1ULL << t) - 1ULL));
                gIdx[b * INN + pos] = c * 64 + t;
            }
            base += __popcll(m);
        }
        if (t == 0) gCount[b] = base;
    }

    // IPackT: one (b,i) entry per thread; coalesced read, scattered store
    {
        const int e = blk * 256 + t;      // 0..131071
        const int b = e >> 10, i = e & 1023;
        float sp = in_spikes[e];
        float dp = (sp > 0.0f) ? 0.0f : delta_pre[e] + 1.0f;
        float Iz = expf(-dp * INV_TAU);
        float Iy = A_TOT * expf(dp * INV_TAU);
        IPackT[(size_t)i * Bb + b] = (rne_bf16(Iz) << 16) | rne_bf16(Iy);
    }

    // transpose: two 32x32 tiles per block
    const int x = t & 31, y = t >> 5;
#pragma unroll
    for (int k = 0; k < 2; k++) {
        int tau = blk * 2 + k;
        int bx = tau & 31, by = tau >> 5;     // bx: i-tile, by: o-tile
        __syncthreads();
#pragma unroll
        for (int j = 0; j < 4; j++)
            tile[y + j * 8][x] = W[(size_t)(by * 32 + y + j * 8) * INN + bx * 32 + x];
        __syncthreads();
#pragma unroll
        for (int j = 0; j < 4; j++)
            Wt[(size_t)(bx * 32 + y + j * 8) * OUTN + by * 32 + x] = tile[x][y + j * 8];
    }
}

// ---------------------------------------------------------------------------
// 2) sparse projection + LIF + OPackT (b-minor). grid (B,4), block (b,z)
//    covers o = z*256+t.
//    OPackT[o*B + b] = (bf16(Oy)<<16) | bf16(Oz), Oy=e^{-df/tau},
//    Oz=-A*e^{df/tau}.
// ---------------------------------------------------------------------------
__global__ __launch_bounds__(256) void spmv_lif_k(
    const float* __restrict__ Wt, const float* __restrict__ membrane,
    const float* __restrict__ delta_fire,
    const int* __restrict__ gIdx, const int* __restrict__ gCount,
    uint32_t* __restrict__ OPackT,
    float* __restrict__ out_spike, float* __restrict__ out_mem) {
    __shared__ int sIdx[INN];
    const int b = blockIdx.x;
    const int z = blockIdx.y;
    const int t = threadIdx.x;
    const int n = gCount[b];
    for (int j = t; j < n; j += 256) sIdx[j] = gIdx[b * INN + j];
    __syncthreads();

    const int o = z * 256 + t;
    float acc = 0.0f;
    int j = 0;
    for (; j + 8 <= n; j += 8) {            // 8 loads in flight
        float w0 = Wt[(size_t)sIdx[j + 0] * OUTN + o];
        float w1 = Wt[(size_t)sIdx[j + 1] * OUTN + o];
        float w2 = Wt[(size_t)sIdx[j + 2] * OUTN + o];
        float w3 = Wt[(size_t)sIdx[j + 3] * OUTN + o];
        float w4 = Wt[(size_t)sIdx[j + 4] * OUTN + o];
        float w5 = Wt[(size_t)sIdx[j + 5] * OUTN + o];
        float w6 = Wt[(size_t)sIdx[j + 6] * OUTN + o];
        float w7 = Wt[(size_t)sIdx[j + 7] * OUTN + o];
        acc += ((w0 + w1) + (w2 + w3)) + ((w4 + w5) + (w6 + w7));
    }
    for (; j < n; j++) acc += Wt[(size_t)sIdx[j] * OUTN + o];

    const int n_bo = b * OUTN + o;
    float mem = membrane[n_bo] * 0.99f + acc;
    float s = (mem > 1.0f) ? 1.0f : 0.0f;
    mem = (s > 0.0f) ? mem - 0.8f : mem;
    out_spike[n_bo] = s;
    out_mem[n_bo] = mem;

    float df = (s > 0.0f) ? 0.0f : delta_fire[n_bo] + 1.0f;
    float Oy = expf(-df * INV_TAU);
    float Oz = -A_TOT * expf(df * INV_TAU);
    OPackT[(size_t)o * Bb + b] = (rne_bf16(Oy) << 16) | rne_bf16(Oz);
}

// ---------------------------------------------------------------------------
// 3) STDP: new_W[o,i] = W[o,i] + sum_b sel(df>dp: Oy*Iy, df<dp: Oz*Iz)
//      min_u32(pO,pI) = selected key, max_u32(pO,pI)<<16 = selected payload.
//    64x32 tile, 4x2 micro (widened on the O side, whose LDS reads are
//    16-lane broadcasts — bank pattern identical to the proven 2x2 kernel).
//    Per 4-b step: 6 x ds_read_b128 = 72 cyc / 32 products = 2.25 cyc/prod
//    (was 3.0), vs VALU floor 2.0 cyc/prod. grid (16,32)=512 blocks,
//    2 blk/CU at 12 KB LDS, 8 waves/CU. XOR swizzle (chunk ^ ((row>>1)&7))
//    keeps staging a bank permutation; i-side read key tx&7 unchanged
//    (conflict-free); the 4 o-broadcast groups use keys {2ty,2ty+1} mod 8 —
//    distinct bank quads per wave. Accumulation order over b is bit-identical
//    to the 2x2 version (cb, c4, k) -> absmax unchanged.
// ---------------------------------------------------------------------------
__global__ __launch_bounds__(256, 2) void stdp_k(
    const float* __restrict__ W, const uint32_t* __restrict__ OPackT,
    const uint32_t* __restrict__ IPackT, float* __restrict__ outW) {
    __shared__ uint32_t sOT[64 * 32];   // [o][b-chunk swz]  8 KB
    __shared__ uint32_t sIT[32 * 32];   // [i][b-chunk swz]  4 KB
    const int t  = threadIdx.x;
    const int o0 = blockIdx.x * 64;
    const int i0 = blockIdx.y * 32;
    const int tx = t & 15;              // i = i0 + 2*tx + {0,1}
    const int ty = t >> 4;              // o = o0 + 4*ty + {0..3}
    const int srow = t >> 3;            // staging row 0..31
    const int sc   = t & 7;             // staging b-chunk 0..7
    const int swr  = (srow >> 1) & 7;   // staging row swizzle key (rows r, r+32 share it)
    const int si   = tx & 7;            // i-read swizzle key (unchanged)
    const int soA  = (2 * ty) & 7;      // o-read key for rows 4ty, 4ty+1
    const int soB  = (2 * ty + 1) & 7;  // o-read key for rows 4ty+2, 4ty+3

    float acc[4][2] = {{0.f, 0.f}, {0.f, 0.f}, {0.f, 0.f}, {0.f, 0.f}};

    for (int cb = 0; cb < Bb / 32; cb++) {         // 4 chunks of 32 b
        const int b0 = cb * 32;
        // stage: sOT rows {srow, srow+32}, sIT row srow; bank-permuted cols
        *(uint4*)&sOT[srow * 32 + ((sc ^ swr) << 2)] =
            *(const uint4*)&OPackT[(size_t)(o0 + srow) * Bb + b0 + 4 * sc];
        *(uint4*)&sOT[(srow + 32) * 32 + ((sc ^ swr) << 2)] =
            *(const uint4*)&OPackT[(size_t)(o0 + srow + 32) * Bb + b0 + 4 * sc];
        *(uint4*)&sIT[srow * 32 + ((sc ^ swr) << 2)] =
            *(const uint4*)&IPackT[(size_t)(i0 + srow) * Bb + b0 + 4 * sc];
        __syncthreads();

#pragma unroll
        for (int c4 = 0; c4 < 8; c4++) {           // 4 b's per step
            const int cA = (c4 ^ soA) << 2;
            const int cB = (c4 ^ soB) << 2;
            const int ci = (c4 ^ si) << 2;
            uint4 oV0 = *(const uint4*)&sOT[(4 * ty + 0) * 32 + cA];
            uint4 oV1 = *(const uint4*)&sOT[(4 * ty + 1) * 32 + cA];
            uint4 oV2 = *(const uint4*)&sOT[(4 * ty + 2) * 32 + cB];
            uint4 oV3 = *(const uint4*)&sOT[(4 * ty + 3) * 32 + cB];
            uint4 iV0 = *(const uint4*)&sIT[(2 * tx + 0) * 32 + ci];
            uint4 iV1 = *(const uint4*)&sIT[(2 * tx + 1) * 32 + ci];
            const uint32_t ov[4][4] = {{oV0.x, oV0.y, oV0.z, oV0.w},
                                       {oV1.x, oV1.y, oV1.z, oV1.w},
                                       {oV2.x, oV2.y, oV2.z, oV2.w},
                                       {oV3.x, oV3.y, oV3.z, oV3.w}};
            const uint32_t iv[2][4] = {{iV0.x, iV0.y, iV0.z, iV0.w},
                                       {iV1.x, iV1.y, iV1.z, iV1.w}};
#pragma unroll
            for (int k = 0; k < 4; k++) {          // bb = b0 + 4*c4 + k
#pragma unroll
                for (int a = 0; a < 4; a++) {
#pragma unroll
                    for (int c = 0; c < 2; c++) {
                        uint32_t kk = min(ov[a][k], iv[c][k]);
                        uint32_t pp = max(ov[a][k], iv[c][k]) << 16;
                        acc[a][c] = fmaf(__uint_as_float(kk),
                                         __uint_as_float(pp), acc[a][c]);
                    }
                }
            }
        }
        __syncthreads();
    }

    // epilogue: new_W = W + acc  (float2 per (o, 2*tx))
#pragma unroll
    for (int a = 0; a < 4; a++) {
        const size_t off = (size_t)(o0 + 4 * ty + a) * INN + i0 + 2 * tx;
        float2 w = *(const float2*)&W[off];
        *(float2*)&outW[off] = make_float2(w.x + acc[a][0], w.y + acc[a][1]);
    }
}

// ---------------------------------------------------------------------------
extern "C" void kernel_launch(void* const* d_in, const int* in_sizes, int n_in,
                              void* d_out, int out_size, void* d_ws, size_t ws_size,
                              hipStream_t stream) {
    const float* in_spikes  = (const float*)d_in[0];
    const float* W          = (const float*)d_in[1];
    const float* membrane   = (const float*)d_in[2];
    const float* delta_pre  = (const float*)d_in[3];
    const float* delta_fire = (const float*)d_in[4];

    float* out_spike = (float*)d_out;                       // (B,OUT)
    float* out_W     = out_spike + (size_t)Bb * OUTN;       // (OUT,IN)
    float* out_mem   = out_W + (size_t)OUTN * INN;          // (B,OUT)

    float* ws        = (float*)d_ws;
    float* Wt        = ws;                                      // 4 MB
    uint32_t* OPackT = (uint32_t*)(Wt + (size_t)INN * OUTN);    // 512 KB
    uint32_t* IPackT = OPackT + (size_t)OUTN * Bb;              // 512 KB
    int* gIdx        = (int*)(IPackT + (size_t)INN * Bb);       // 512 KB
    int* gCount      = gIdx + (size_t)Bb * INN;                 // 512 B

    hipLaunchKernelGGL(prep_k, dim3(512), dim3(256), 0, stream,
                       W, in_spikes, delta_pre, Wt, IPackT, gIdx, gCount);
    hipLaunchKernelGGL(spmv_lif_k, dim3(Bb, 4), dim3(256), 0, stream,
                       Wt, membrane, delta_fire, gIdx, gCount,
                       OPackT, out_spike, out_mem);
    hipLaunchKernelGGL(stdp_k, dim3(OUTN / 64, INN / 32), dim3(256), 0, stream,
                       W, OPackT, IPackT, out_W);
}